// Round 2
// baseline (325.941 us; speedup 1.0000x reference)
//
#include <hip/hip_runtime.h>

// Pure permutation for KernelActivation (k=2), 16B-per-lane on both sides.
// out group G=(b,i,j,w) is float4 {x[b,2i,2j,w], x[b,2i,2j+1,w], x[b,2i+1,2j,w], x[b,2i+1,2j+1,w]}
//
// Work assignment: each quad of lanes (r = gid&3) handles one w-quad Q = gid>>2.
// Lane r loads float4 of input row r (r = p*2+q: rc=r>>1 channel offset, rh=r&1 h offset)
// at w = wq*4..wq*4+3. A 4x4 in-quad transpose (2 butterfly rounds of __shfl_xor)
// leaves lane e with the float4 for w=wq*4+e, which is exactly out[gid] -> stores
// stay perfectly unit-stride (1KB/wave/instruction). Loads are dwordx4: per wave,
// 4 contiguous 256B streams per instruction.

constexpr int ROW4 = 224 / 4;        // 56  float4 per image row
constexpr int PLANE4 = 224 * 224 / 4; // 12544 float4 per (b,c) plane

__global__ __launch_bounds__(256)
void permute_kernel(const float4* __restrict__ x4, float4* __restrict__ out) {
    int gid = blockIdx.x * 256 + threadIdx.x;
    int r = gid & 3;       // lane-in-quad = input row index (p*2+q)
    int Q = gid >> 2;      // global w-quad index

    int wq = Q % 56;
    int t  = Q / 56;
    int j  = t % 112;
    int u  = t / 112;
    int i  = u & 31;
    int b  = u >> 5;

    int rc = r >> 1, rh = r & 1;
    int src = (b * 64 + 2 * i + rc) * PLANE4 + (2 * j + rh) * ROW4 + wq;
    float4 v = x4[src];

    // 4x4 transpose across the quad.
    // Phase 1 (xor 2): swap off-diagonal 2x2 blocks.
    float s0 = (r & 2) ? v.x : v.z;
    float s1 = (r & 2) ? v.y : v.w;
    s0 = __shfl_xor(s0, 2);
    s1 = __shfl_xor(s1, 2);
    if (r & 2) { v.x = s0; v.y = s1; } else { v.z = s0; v.w = s1; }

    // Phase 2 (xor 1): transpose each 2x2 sub-block.
    float t0 = (r & 1) ? v.x : v.y;
    float t1 = (r & 1) ? v.z : v.w;
    t0 = __shfl_xor(t0, 1);
    t1 = __shfl_xor(t1, 1);
    if (r & 1) { v.x = t0; v.z = t1; } else { v.y = t0; v.w = t1; }

    out[gid] = v;
}

extern "C" void kernel_launch(void* const* d_in, const int* in_sizes, int n_in,
                              void* d_out, int out_size, void* d_ws, size_t ws_size,
                              hipStream_t stream) {
    const float4* x4 = (const float4*)d_in[0];
    float4* out = (float4*)d_out;

    int n_threads = out_size / 4;            // 12,845,056 (one float4 per thread)
    int block = 256;
    int grid = n_threads / block;            // 50,176 exactly (no tail)

    permute_kernel<<<grid, block, 0, stream>>>(x4, out);
}